// Round 5
// baseline (81.512 us; speedup 1.0000x reference)
//
#include <hip/hip_runtime.h>
#include <math.h>

typedef __attribute__((ext_vector_type(8))) short short8;
typedef __attribute__((ext_vector_type(4))) float f32x4;

#define GLOBAL_AS __attribute__((address_space(1)))
#define LDS_AS __attribute__((address_space(3)))

__device__ inline short f2bf(float f) {
    unsigned u = __float_as_uint(f);
    u += 0x7FFFu + ((u >> 16) & 1u);   // RNE to bf16
    return (short)(u >> 16);
}

// ------ Kernel 1: cast centers (f32->bf16) + chalf[k] = 0.5*sum(c^2) in f32 ------
__global__ __launch_bounds__(256) void cast_centers_kernel(const float* __restrict__ c,
                                                           short* __restrict__ cb,
                                                           float* __restrict__ chalf, int dim) {
    int k = blockIdx.x;
    int t = threadIdx.x;
    const float* row = c + (size_t)k * dim;
    short* orow = cb + (size_t)k * dim;
    float s = 0.f;
    for (int i = t * 4; i < dim; i += blockDim.x * 4) {
        float4 v = *(const float4*)(row + i);
        s += v.x * v.x + v.y * v.y + v.z * v.z + v.w * v.w;
        short4 o;
        o.x = f2bf(v.x); o.y = f2bf(v.y); o.z = f2bf(v.z); o.w = f2bf(v.w);
        *(short4*)(orow + i) = o;
    }
#pragma unroll
    for (int off = 32; off; off >>= 1) s += __shfl_xor(s, off);
    __shared__ float red[4];
    if ((t & 63) == 0) red[t >> 6] = s;
    __syncthreads();
    if (t == 0) chalf[k] = 0.5f * (red[0] + red[1] + red[2] + red[3]);
}

// ------------- Kernel 2: fused GEMM (64 x FULL-ROW 1024) + log-softmax epilogue -------------
// logits[b,k] = x_b . c_k - 0.5*||c_k||^2  (row-constant -0.5*||x||^2 cancels in log_softmax)
// out[b,k] = logits[b,k] - logsumexp_k(logits[b,:])
//
// Pipeline: staging unit = HALF (32 KB): 512 center-rows (bit6 of row = half parity) x 32 K.
// Ring-4 B half-slots (128 KB) + ring-2 A unit-slots (8 KB). Depth-3 counted vmcnt(9)
// (T4) -- never drain to 0 in steady state. Per half: {frag ds_reads, issue GLD for
// half H+3, barrier, setprio+16 MFMA, vmcnt(9), barrier}.
// A: f32 read once from HBM, cvt->bf16 ds_write 1 unit ahead (no cast kernel).
// Swizzle (both-sides, rule #21): 16B chunk s of LDS row i stored at s ^ ((i>>1)&3).
#define BM 64
#define UK 32
#define BSLOT 32768
#define ABASE 131072   // 4 * BSLOT

__global__ __launch_bounds__(512, 2) void fused_kernel(
    const float* __restrict__ x,     // [M][K] f32
    const short* __restrict__ cb,    // [N][K] bf16
    const float* __restrict__ chalf, // [N]
    float* __restrict__ out,         // [M][N]
    int M, int N, int K) {
    __shared__ char lds[139264];
    const int t = threadIdx.x;
    const int l = t & 63, w = t >> 6, lr = l & 15, hi = l >> 4;
    const int brow = blockIdx.x * BM;
    const size_t rowb = (size_t)K * 2;

    // ---- fragment-read offsets (swizzle chunk: hi ^ ((row>>1)&3), row%16 == lr) ----
    const int sw = (hi ^ ((lr >> 1) & 3)) << 4;
    const int bfb = (w * 64 + lr) * 64 + sw;      // + (n&3)*1024 + slot*BSLOT
    const int afb = ABASE + lr * 64 + sw;         // + m*1024 + (u&1)*4096

    // ---- A stage: thread t covers row t>>3, f32 cols (t&7)*4.. ----
    const int ar = t >> 3, ac = t & 7;
    const float* xsrc = x + (size_t)(brow + ar) * K + ac * 4;
    const int awofs = ABASE + ar * 64 + (((ac >> 1) ^ ((ar >> 1) & 3)) << 4) + (ac & 1) * 8;

    // ---- B stage: half p holds center rows with bit6==p; local row i -> global
    // row ((i>>6)<<7)|(p<<6)|(i&63). Thread t, GLD j: i = j*128 + (t>>2). ----
    const int Lg = (t & 3) ^ ((t >> 3) & 3);              // inverse swizzle on source
    const int r0 = (t >> 8) * 128 + ((t >> 2) & 63);
    const char* bsrc0 = (const char*)cb + (size_t)r0 * rowb + Lg * 16;
    const char* bsrc1 = bsrc0 + 64 * rowb;
    const size_t bjs = 256 * rowb;

#define GLD(gp, lo) __builtin_amdgcn_global_load_lds((const GLOBAL_AS int*)(gp), \
                        (LDS_AS int*)(lds + (lo)), 16, 0, 0)
#define STAGEH(bp, ku, sl) do {                                                 \
    _Pragma("unroll")                                                           \
    for (int j = 0; j < 4; ++j)                                                 \
        GLD((bp) + (size_t)j * bjs + (size_t)(ku) * 64, (sl)*BSLOT + j*8192 + t*16); \
    } while (0)
#define AWRITE(sl, fv) do {                                                     \
    short4 v_; v_.x = f2bf((fv).x); v_.y = f2bf((fv).y);                        \
    v_.z = f2bf((fv).z); v_.w = f2bf((fv).w);                                   \
    *(short4*)(lds + awofs + (sl)*4096) = v_; } while (0)

    f32x4 acc[4][8];
#pragma unroll
    for (int m = 0; m < 4; ++m)
#pragma unroll
        for (int n = 0; n < 8; ++n)
#pragma unroll
            for (int q = 0; q < 4; ++q) acc[m][n][q] = 0.f;

    const int nt = K / UK;                   // 32 units = 64 halves
    float4 faCur;
    {   // prologue: stage halves 0,1,2; A unit 0; load fa(unit 1)
        float4 fa0 = *(const float4*)(xsrc);
        STAGEH(bsrc0, 0, 0);
        STAGEH(bsrc1, 0, 1);
        STAGEH(bsrc0, 1, 2);
        faCur = *(const float4*)(xsrc + UK);
        AWRITE(0, fa0);
        asm volatile("s_waitcnt vmcnt(9)" ::: "memory");   // half 0 landed
        asm volatile("s_waitcnt lgkmcnt(0)" ::: "memory"); // A unit 0 visible
    }
    __builtin_amdgcn_s_barrier();

    for (int u = 0; u < nt; ++u) {
        const int sA = ((2 * u) & 3) * BSLOT;
        const int sB = ((2 * u + 1) & 3) * BSLOT;
        const char* Ab = lds + (u & 1) * 4096;
        short8 af[4], bf0[4], bf1[4];
        float4 faN = faCur;
        // ================= half A (data-half 2u): MFMA n0..3 =================
        if (u <= 29) faN = *(const float4*)(xsrc + (size_t)(u + 2) * UK);
#pragma unroll
        for (int m = 0; m < 4; ++m) af[m] = *(const short8*)(Ab + afb + m * 1024);
#pragma unroll
        for (int n = 0; n < 4; ++n) bf0[n] = *(const short8*)(lds + sA + bfb + n * 1024);
        if (u <= 30) STAGEH(bsrc1, u + 1, (2 * u + 3) & 3);
        __builtin_amdgcn_s_barrier();
        __builtin_amdgcn_s_setprio(1);
#pragma unroll
        for (int m = 0; m < 4; ++m)
#pragma unroll
            for (int n = 0; n < 4; ++n)
                acc[m][n] = __builtin_amdgcn_mfma_f32_16x16x32_bf16(af[m], bf0[n], acc[m][n], 0, 0, 0);
        __builtin_amdgcn_s_setprio(0);
        if (u <= 29)      { asm volatile("s_waitcnt vmcnt(9)" ::: "memory"); }
        else if (u == 30) { asm volatile("s_waitcnt vmcnt(8)" ::: "memory"); }
        else              { asm volatile("s_waitcnt vmcnt(0)" ::: "memory"); }
        __builtin_amdgcn_s_barrier();
        // ================= half B (data-half 2u+1): MFMA n4..7 =================
#pragma unroll
        for (int n = 0; n < 4; ++n) bf1[n] = *(const short8*)(lds + sB + bfb + n * 1024);
        if (u <= 29) STAGEH(bsrc0, u + 2, (2 * u + 4) & 3);
        if (u <= 30) AWRITE((u + 1) & 1, faCur);
        __builtin_amdgcn_s_barrier();
        __builtin_amdgcn_s_setprio(1);
#pragma unroll
        for (int m = 0; m < 4; ++m)
#pragma unroll
            for (int n = 0; n < 4; ++n)
                acc[m][n + 4] = __builtin_amdgcn_mfma_f32_16x16x32_bf16(af[m], bf1[n], acc[m][n + 4], 0, 0, 0);
        __builtin_amdgcn_s_setprio(0);
        if (u <= 29)      { asm volatile("s_waitcnt vmcnt(9)" ::: "memory"); }
        else if (u == 30) { asm volatile("s_waitcnt vmcnt(4)" ::: "memory"); }
        asm volatile("s_waitcnt lgkmcnt(0)" ::: "memory");   // A ds_write visible
        __builtin_amdgcn_s_barrier();
        faCur = faN;
    }

    // ================= fused log-softmax epilogue =================
    // C/D frag layout: col = lane&15, row = (lane>>4)*4 + q.
    // Lane holds rows R = m*16 + hi*4 + q, cols w*128 + n*16 + lr.
    float ch[8];
#pragma unroll
    for (int n = 0; n < 8; ++n) ch[n] = chalf[w * 128 + n * 16 + lr];

    // pass 1: per-lane max over n, reduce over lr-lanes, cross-wave via LDS
    float pm[4][4];
#pragma unroll
    for (int m = 0; m < 4; ++m)
#pragma unroll
        for (int q = 0; q < 4; ++q) {
            float v = acc[m][0][q] - ch[0];
#pragma unroll
            for (int n = 1; n < 8; ++n) v = fmaxf(v, acc[m][n][q] - ch[n]);
            pm[m][q] = v;
        }
#pragma unroll
    for (int d = 1; d <= 8; d <<= 1)
#pragma unroll
        for (int m = 0; m < 4; ++m)
#pragma unroll
            for (int q = 0; q < 4; ++q) pm[m][q] = fmaxf(pm[m][q], __shfl_xor(pm[m][q], d));
    if (lr == 0) {
#pragma unroll
        for (int m = 0; m < 4; ++m)
#pragma unroll
            for (int q = 0; q < 4; ++q)
                *(float*)(lds + (m * 16 + hi * 4 + q) * 32 + w * 4) = pm[m][q];   // wmax[R][w]
    }
    __syncthreads();
    if (t < 64) {
        float4 a = *(const float4*)(lds + t * 32);
        float4 b = *(const float4*)(lds + t * 32 + 16);
        float g = fmaxf(fmaxf(fmaxf(a.x, a.y), fmaxf(a.z, a.w)),
                        fmaxf(fmaxf(b.x, b.y), fmaxf(b.z, b.w)));
        *(float*)(lds + 4096 + t * 4) = g;                                        // gmax[R]
    }
    __syncthreads();

    // pass 2: sum of exp
    float ps[4][4];
#pragma unroll
    for (int m = 0; m < 4; ++m)
#pragma unroll
        for (int q = 0; q < 4; ++q) {
            const float g = *(const float*)(lds + 4096 + (m * 16 + hi * 4 + q) * 4);
            float s = 0.f;
#pragma unroll
            for (int n = 0; n < 8; ++n) s += __expf(acc[m][n][q] - ch[n] - g);
            ps[m][q] = s;
        }
#pragma unroll
    for (int d = 1; d <= 8; d <<= 1)
#pragma unroll
        for (int m = 0; m < 4; ++m)
#pragma unroll
            for (int q = 0; q < 4; ++q) ps[m][q] += __shfl_xor(ps[m][q], d);
    if (lr == 0) {
#pragma unroll
        for (int m = 0; m < 4; ++m)
#pragma unroll
            for (int q = 0; q < 4; ++q)
                *(float*)(lds + 2048 + (m * 16 + hi * 4 + q) * 32 + w * 4) = ps[m][q]; // wsum[R][w]
    }
    __syncthreads();
    if (t < 64) {
        float4 a = *(const float4*)(lds + 2048 + t * 32);
        float4 b = *(const float4*)(lds + 2048 + t * 32 + 16);
        float s = (a.x + a.y + a.z + a.w) + (b.x + b.y + b.z + b.w);
        *(float*)(lds + 4352 + t * 4) = *(const float*)(lds + 4096 + t * 4) + __logf(s); // lse[R]
    }
    __syncthreads();

    // write final output
#pragma unroll
    for (int m = 0; m < 4; ++m)
#pragma unroll
        for (int q = 0; q < 4; ++q) {
            const int R = m * 16 + hi * 4 + q;
            const float lse = *(const float*)(lds + 4352 + R * 4);
            float* orow = out + (size_t)(brow + R) * N + w * 128 + lr;
#pragma unroll
            for (int n = 0; n < 8; ++n)
                orow[n * 16] = acc[m][n][q] - ch[n] - lse;
        }
#undef STAGEH
#undef AWRITE
#undef GLD
}

extern "C" void kernel_launch(void* const* d_in, const int* in_sizes, int n_in,
                              void* d_out, int out_size, void* d_ws, size_t ws_size,
                              hipStream_t stream) {
    const float* x = (const float*)d_in[0];
    const float* c = (const float*)d_in[1];
    float* out = (float*)d_out;

    int dim = (int)(sqrt((double)in_sizes[1]) + 0.5);   // 1024
    int batch = in_sizes[0] / dim;                      // 16384

    // workspace layout: [centers bf16][chalf f32]
    size_t cb_bytes = (size_t)dim * dim * 2;
    short* cb = (short*)d_ws;
    float* chalf = (float*)((char*)d_ws + cb_bytes);

    cast_centers_kernel<<<dim, 256, 0, stream>>>(c, cb, chalf, dim);

    fused_kernel<<<batch / BM, 512, 0, stream>>>(x, cb, chalf, out, batch, dim, dim);
}